// Round 18
// baseline (520.783 us; speedup 1.0000x reference)
//
#include <hip/hip_runtime.h>

#define NAGENTS 8
#define NM 128          // NAGENTS*MITEMS
#define MENU 256
#define SFULL 257       // MENU + null entry

typedef float f32x4 __attribute__((ext_vector_type(4)));

// Raw barrier: wait LDS ops only (no vmcnt drain — copy-out stores and any
// in-flight loads keep flying across phases).
#define BAR() asm volatile("s_waitcnt lgkmcnt(0)\n\ts_barrier" ::: "memory")

// 256 threads/block, one auction per block, (256,6) => ~84 VGPR cap, 24
// waves/CU (R17: occupancy beyond this is not the limiter). Streaming pass
// grouped into 4-chunk RUNS: 4 loads (4KB read run) -> 4 stores (4KB write
// run) -> compute. Rationale: all prior fast variants alternate 1KB read /
// 1KB write per chunk => maximal HBM R/W bus turnaround; batching runs 4x
// reduces turnarounds. Prior batch tests were invalidated by nt-store RMW
// (R8) and VGPR spill at the 64-cap (R13); this is the clean test.
// Fully-online softmax families (R15): no pwT, tiny merge tail.
__global__ __launch_bounds__(256, 6) void cama_kernel(
    const float* __restrict__ bids,   // B,8,16
    const float* __restrict__ allocs, // B,256,8,16
    const float* __restrict__ wvec,   // B,8
    const float* __restrict__ bvec,   // B,256
    const float* __restrict__ tempp,  // 1
    float* __restrict__ out, int Bsz)
{
    __shared__ float lds_tot[MENU];                  // 1KB
    __shared__ float lds_bb[MENU];                   // 1KB
    __shared__ __align__(16) float4 lds_accs[4][32]; // 2KB item partials
    __shared__ __align__(16) float4 lds_w1[4];       // per-wave (M1,Z1,Sab,-)
    __shared__ __align__(16) float4 lds_loo[4][8];   // per-wave (M2,Z2,S1,S2)
    __shared__ float lds_scw[4][8];                  // per-wave Scw[n]
    __shared__ float lds_rcs[NAGENTS], lds_rb[NAGENTS], lds_cw[NAGENTS];
    __shared__ float lds_ab;
    __shared__ float2 lds_mzf;                       // (M1f, 1/Z1f)

    const int u = threadIdx.x;    // 0..255
    const int lane = u & 63;
    const int wave = u >> 6;      // 0..3
    const int c = u & 31;         // n = c>>2, item-quad mq = u&3
    const int n = c >> 2;
    const int mq = u & 3;
    const int su = u >> 5;        // s = 8k + su
    const size_t bb_ = (size_t)blockIdx.x;

    float* out_choice = out;                                  // B*257
    float* out_item   = out + (size_t)Bsz * SFULL;            // B*128
    float* out_pay    = out_item + (size_t)Bsz * NM;          // 8*B
    float* out_all    = out_pay + (size_t)NAGENTS * Bsz;      // B*257*128
    f32x4* out_all4   = (f32x4*)out_all + bb_ * 8224;
    const f32x4* src4 = (const f32x4*)allocs + bb_ * 8192;

    const float temp = tempp[0];
    lds_bb[u] = bvec[bb_ * MENU + u];                    // 256 = blockDim
    const float4 q4 = ((const float4*)(bids + bb_ * NM))[c];   // L1 broadcast
    const float w_n = wvec[bb_ * NAGENTS + n];
    BAR();   // bb staged

    // online states
    float M1 = -1e30f, Z1 = 0.f, Sab = 0.f, Scw = 0.f;
    float4 A = make_float4(0.f, 0.f, 0.f, 0.f);
    float M2 = -1e30f, Z2 = 0.f, S1 = 0.f, S2 = 0.f;

    // ---- pass 1: streaming in 4-chunk runs (read run / write run / compute)
#pragma unroll
    for (int g = 0; g < 8; ++g) {
        f32x4 buf[4];
#pragma unroll
        for (int j = 0; j < 4; ++j)
            buf[j] = src4[(((g << 2) + j) << 8) + u];
#pragma unroll
        for (int j = 0; j < 4; ++j)
            out_all4[(((g << 2) + j) << 8) + u] = buf[j];
#pragma unroll
        for (int j = 0; j < 4; ++j) {
            const int s = (((g << 2) + j) << 3) + su;
            const float bbs = lds_bb[s];
            float util = buf[j][0]*q4.x + buf[j][1]*q4.y
                       + buf[j][2]*q4.z + buf[j][3]*q4.w;
            util += __shfl_xor(util, 1);
            util += __shfl_xor(util, 2);           // item-dot for (s,n)
            float pwv = w_n * util;
            float t = pwv;
            t += __shfl_xor(t, 4);
            t += __shfl_xor(t, 8);
            t += __shfl_xor(t, 16);                // tot[s], all lanes
            if (c == 0) lds_tot[s] = t;
            // full-softmax family
            float x = (t + bbs) * temp;
            float mn = fmaxf(M1, x);
            float sc = __expf(M1 - mn);
            float p  = __expf(x - mn);
            Z1  = Z1*sc + p;
            A.x = A.x*sc + p*buf[j][0];
            A.y = A.y*sc + p*buf[j][1];
            A.z = A.z*sc + p*buf[j][2];
            A.w = A.w*sc + p*buf[j][3];
            Sab = Sab*sc + p*bbs;
            Scw = Scw*sc + p*pwv;
            M1 = mn;
            // leave-one-out family (own agent n)
            float tr = t - pwv;
            float x2 = (tr + bbs) * temp;
            float mn2 = fmaxf(M2, x2);
            float sc2 = __expf(M2 - mn2);
            float p2  = __expf(x2 - mn2);
            Z2 = Z2*sc2 + p2;
            S1 = S1*sc2 + p2*tr;
            S2 = S2*sc2 + p2*bbs;
            M2 = mn2;
        }
    }
    if (u < 32) {
        f32x4 z4 = {0.f, 0.f, 0.f, 0.f};
        out_all4[8192 + u] = z4;                   // null row of the copy
    }

    // ---- su-pair merge (lane <-> lane^32), then per-wave partials to LDS ----
    {
        float Mo = __shfl_xor(M1, 32), Zo = __shfl_xor(Z1, 32);
        float Sabo = __shfl_xor(Sab, 32), Scwo = __shfl_xor(Scw, 32);
        float ax = __shfl_xor(A.x, 32), ay = __shfl_xor(A.y, 32);
        float az = __shfl_xor(A.z, 32), aw = __shfl_xor(A.w, 32);
        float mn = fmaxf(M1, Mo);
        float s0 = __expf(M1 - mn), s1 = __expf(Mo - mn);
        Z1  = Z1*s0  + Zo*s1;
        Sab = Sab*s0 + Sabo*s1;
        Scw = Scw*s0 + Scwo*s1;
        A.x = A.x*s0 + ax*s1;  A.y = A.y*s0 + ay*s1;
        A.z = A.z*s0 + az*s1;  A.w = A.w*s0 + aw*s1;
        M1 = mn;

        float Mo2 = __shfl_xor(M2, 32), Zo2 = __shfl_xor(Z2, 32);
        float S1o = __shfl_xor(S1, 32), S2o = __shfl_xor(S2, 32);
        float mn2 = fmaxf(M2, Mo2);
        float t0 = __expf(M2 - mn2), t1 = __expf(Mo2 - mn2);
        Z2 = Z2*t0 + Zo2*t1;
        S1 = S1*t0 + S1o*t1;
        S2 = S2*t0 + S2o*t1;
        M2 = mn2;

        if (lane < 32) {
            lds_accs[wave][c] = make_float4(A.x, A.y, A.z, A.w);
            if (c == 0) lds_w1[wave] = make_float4(M1, Z1, Sab, 0.f);
            if (mq == 0) {
                lds_scw[wave][n] = Scw;
                lds_loo[wave][n] = make_float4(M2, Z2, S1, S2);
            }
        }
    }
    BAR();   // b1: tot + all per-wave partials ready

    // ---- stage A: final merges ----
    if (u < 32) {
        // item_allocation (+ u==0: ab, mzf)
        float4 w1 = lds_w1[0];
        float Mm = w1.x, Zm = w1.y, Sabm = w1.z;
        float4 Am = lds_accs[0][u];
#pragma unroll
        for (int j = 1; j < 4; ++j) {
            float4 wj = lds_w1[j];
            float4 Aj = lds_accs[j][u];
            float mn = fmaxf(Mm, wj.x);
            float s0 = __expf(Mm - mn), s1 = __expf(wj.x - mn);
            Zm   = Zm*s0   + wj.y*s1;
            Sabm = Sabm*s0 + wj.z*s1;
            Am.x = Am.x*s0 + Aj.x*s1;  Am.y = Am.y*s0 + Aj.y*s1;
            Am.z = Am.z*s0 + Aj.z*s1;  Am.w = Am.w*s0 + Aj.w*s1;
            Mm = mn;
        }
        float M1f = fmaxf(Mm, 0.f);                // null entry x=0
        float s0 = __expf(Mm - M1f);
        float Z1f = Zm*s0 + __expf(-M1f);
        float inv = 1.f / Z1f;
        float sf = s0 * inv;
        ((float4*)(out_item + bb_ * NM))[u] =
            make_float4(Am.x*sf, Am.y*sf, Am.z*sf, Am.w*sf);
        if (u == 0) {
            lds_ab = Sabm * sf;
            lds_mzf = make_float2(M1f, inv);
        }
    } else if (u < 40) {
        // LOO finalize for agent i
        const int i = u - 32;
        float4 L = lds_loo[0][i];
        float Mm = L.x, Zm = L.y, S1m = L.z, S2m = L.w;
#pragma unroll
        for (int j = 1; j < 4; ++j) {
            float4 Lj = lds_loo[j][i];
            float mn = fmaxf(Mm, Lj.x);
            float s0 = __expf(Mm - mn), s1 = __expf(Lj.x - mn);
            Zm  = Zm*s0  + Lj.y*s1;
            S1m = S1m*s0 + Lj.z*s1;
            S2m = S2m*s0 + Lj.w*s1;
            Mm = mn;
        }
        float M2f = fmaxf(Mm, 0.f);                // null: tr=0, b=0
        float s0 = __expf(Mm - M2f);
        float Z2f = Zm*s0 + __expf(-M2f);
        lds_rcs[i] = S1m*s0 / Z2f;
        lds_rb[i]  = S2m*s0 / Z2f;
    } else if (u < 48) {
        // chosen-welfare finalize for agent i
        const int i = u - 40;
        float4 w1 = lds_w1[0];
        float Mm = w1.x, Zm = w1.y;
        float Sm = lds_scw[0][i];
#pragma unroll
        for (int j = 1; j < 4; ++j) {
            float4 wj = lds_w1[j];
            float mn = fmaxf(Mm, wj.x);
            float s0 = __expf(Mm - mn), s1 = __expf(wj.x - mn);
            Zm = Zm*s0 + wj.y*s1;
            Sm = Sm*s0 + lds_scw[j][i]*s1;
            Mm = mn;
        }
        float M1f = fmaxf(Mm, 0.f);
        float s0 = __expf(Mm - M1f);
        float Z1f = Zm*s0 + __expf(-M1f);
        lds_cw[i] = Sm*s0 / Z1f;
    }
    BAR();   // b2: ab/mzf/rcs/rb/cw ready

    // ---- stage B: out_choice (all threads) + payments (8 threads) ----
    {
        float2 mzf = lds_mzf;
        float x = (lds_tot[u] + lds_bb[u]) * temp;
        out_choice[bb_ * SFULL + u] = __expf(x - mzf.x) * mzf.y;
        if (u == 0)
            out_choice[bb_ * SFULL + MENU] = __expf(-mzf.x) * mzf.y;
    }
    if (u < NAGENTS) {
        float ctot = 0.f;
#pragma unroll
        for (int k = 0; k < NAGENTS; ++k) ctot += lds_cw[k];
        float pay = (lds_rcs[u] + lds_rb[u] - (ctot - lds_cw[u]) - lds_ab)
                    / wvec[bb_ * NAGENTS + u];
        out_pay[(size_t)u * Bsz + bb_] = pay;
    }
}

extern "C" void kernel_launch(void* const* d_in, const int* in_sizes, int n_in,
                              void* d_out, int out_size, void* d_ws, size_t ws_size,
                              hipStream_t stream) {
    const float* bids   = (const float*)d_in[0];
    const float* allocs = (const float*)d_in[1];
    const float* wvec   = (const float*)d_in[2];
    const float* bvec   = (const float*)d_in[3];
    const float* tempp  = (const float*)d_in[4];
    float* out = (float*)d_out;
    const int Bsz = in_sizes[0] / NM;          // 4096
    cama_kernel<<<Bsz, 256, 0, stream>>>(bids, allocs, wvec, bvec, tempp,
                                         out, Bsz);
}

// Round 19
// 228.245 us; speedup vs baseline: 2.2817x; 2.2817x over previous
//
#include <hip/hip_runtime.h>

#define NAGENTS 8
#define NM 128          // NAGENTS*MITEMS
#define MENU 256
#define SFULL 257       // MENU + null entry

typedef float f32x4 __attribute__((ext_vector_type(4)));

// Raw barrier: wait LDS ops only (no vmcnt drain — copy-out stores and any
// in-flight loads keep flying across phases).
#define BAR() asm volatile("s_waitcnt lgkmcnt(0)\n\ts_barrier" ::: "memory")

// 256 threads/block, one auction per block, (256,6). The streaming pass is
// driven by ONE inline-asm block per 4-chunk group:
//   4x global_load_dwordx4  ->  s_waitcnt vmcnt(0)  ->  4x global_store_dwordx4
// This pins a 4KB-read-run / 4KB-write-run pattern at the instruction level.
// Rationale: hipcc sabotages every C-level batch (R8/R13/R18: VGPR_Count
// 32-40 « live set, ~2x WRITE amplification from scheduling/spill); asm with
// early-clobber "v" outputs and the waitcnt INSIDE the block (guide rule #18)
// is the only way to run the R/W-turnaround experiment cleanly.
// Fully-online softmax families (R15); merge tail unchanged.
__global__ __launch_bounds__(256, 6) void cama_kernel(
    const float* __restrict__ bids,   // B,8,16
    const float* __restrict__ allocs, // B,256,8,16
    const float* __restrict__ wvec,   // B,8
    const float* __restrict__ bvec,   // B,256
    const float* __restrict__ tempp,  // 1
    float* __restrict__ out, int Bsz)
{
    __shared__ float lds_tot[MENU];                  // 1KB
    __shared__ float lds_bb[MENU];                   // 1KB
    __shared__ __align__(16) float4 lds_accs[4][32]; // 2KB item partials
    __shared__ __align__(16) float4 lds_w1[4];       // per-wave (M1,Z1,Sab,-)
    __shared__ __align__(16) float4 lds_loo[4][8];   // per-wave (M2,Z2,S1,S2)
    __shared__ float lds_scw[4][8];                  // per-wave Scw[n]
    __shared__ float lds_rcs[NAGENTS], lds_rb[NAGENTS], lds_cw[NAGENTS];
    __shared__ float lds_ab;
    __shared__ float2 lds_mzf;                       // (M1f, 1/Z1f)

    const int u = threadIdx.x;    // 0..255
    const int lane = u & 63;
    const int wave = u >> 6;      // 0..3
    const int c = u & 31;         // n = c>>2, item-quad mq = u&3
    const int n = c >> 2;
    const int mq = u & 3;
    const int su = u >> 5;        // s = 8k + su
    const size_t bb_ = (size_t)blockIdx.x;

    float* out_choice = out;                                  // B*257
    float* out_item   = out + (size_t)Bsz * SFULL;            // B*128
    float* out_pay    = out_item + (size_t)Bsz * NM;          // 8*B
    float* out_all    = out_pay + (size_t)NAGENTS * Bsz;      // B*257*128
    const float* src_base = allocs + bb_ * (MENU * NM);       // this block's payload
    float* dst_base = out_all + bb_ * (SFULL * NM);           // copy-out target

    const float temp = tempp[0];
    lds_bb[u] = bvec[bb_ * MENU + u];                    // 256 = blockDim
    const float4 q4 = ((const float4*)(bids + bb_ * NM))[c];   // L1 broadcast
    const float w_n = wvec[bb_ * NAGENTS + n];
    BAR();   // bb staged

    // online states
    float M1 = -1e30f, Z1 = 0.f, Sab = 0.f, Scw = 0.f;
    float4 A = make_float4(0.f, 0.f, 0.f, 0.f);
    float M2 = -1e30f, Z2 = 0.f, S1 = 0.f, S2 = 0.f;

    const int u16 = u << 4;   // byte offset of this thread's float4 in a chunk

    // ---- pass 1: streaming via pinned 4-load-run / 4-store-run asm groups ----
    for (int g = 0; g < 8; ++g) {
        const int o0 = (g << 14) + u16;          // chunk 4g+0, bytes
        const int o1 = o0 + 4096;
        const int o2 = o0 + 8192;
        const int o3 = o0 + 12288;
        f32x4 b0, b1, b2, b3;
        asm volatile(
            "global_load_dwordx4 %0, %4, %8 offset:0\n\t"
            "global_load_dwordx4 %1, %5, %8 offset:0\n\t"
            "global_load_dwordx4 %2, %6, %8 offset:0\n\t"
            "global_load_dwordx4 %3, %7, %8 offset:0\n\t"
            "s_waitcnt vmcnt(0)\n\t"
            "global_store_dwordx4 %4, %0, %9 offset:0\n\t"
            "global_store_dwordx4 %5, %1, %9 offset:0\n\t"
            "global_store_dwordx4 %6, %2, %9 offset:0\n\t"
            "global_store_dwordx4 %7, %3, %9 offset:0"
            : "=&v"(b0), "=&v"(b1), "=&v"(b2), "=&v"(b3)
            : "v"(o0), "v"(o1), "v"(o2), "v"(o3),
              "s"(src_base), "s"(dst_base)
            : "memory");

        f32x4 bufs0 = b0, bufs1 = b1, bufs2 = b2, bufs3 = b3;
#pragma unroll
        for (int j = 0; j < 4; ++j) {
            f32x4 a4 = (j == 0) ? bufs0 : (j == 1) ? bufs1 : (j == 2) ? bufs2 : bufs3;
            const int s = (((g << 2) + j) << 3) + su;
            const float bbs = lds_bb[s];
            float util = a4[0]*q4.x + a4[1]*q4.y + a4[2]*q4.z + a4[3]*q4.w;
            util += __shfl_xor(util, 1);
            util += __shfl_xor(util, 2);           // item-dot for (s,n)
            float pwv = w_n * util;
            float t = pwv;
            t += __shfl_xor(t, 4);
            t += __shfl_xor(t, 8);
            t += __shfl_xor(t, 16);                // tot[s], all lanes
            if (c == 0) lds_tot[s] = t;
            // full-softmax family
            float x = (t + bbs) * temp;
            float mn = fmaxf(M1, x);
            float sc = __expf(M1 - mn);
            float p  = __expf(x - mn);
            Z1  = Z1*sc + p;
            A.x = A.x*sc + p*a4[0];
            A.y = A.y*sc + p*a4[1];
            A.z = A.z*sc + p*a4[2];
            A.w = A.w*sc + p*a4[3];
            Sab = Sab*sc + p*bbs;
            Scw = Scw*sc + p*pwv;
            M1 = mn;
            // leave-one-out family (own agent n)
            float tr = t - pwv;
            float x2 = (tr + bbs) * temp;
            float mn2 = fmaxf(M2, x2);
            float sc2 = __expf(M2 - mn2);
            float p2  = __expf(x2 - mn2);
            Z2 = Z2*sc2 + p2;
            S1 = S1*sc2 + p2*tr;
            S2 = S2*sc2 + p2*bbs;
            M2 = mn2;
        }
    }
    if (u < 32) {
        f32x4 z4 = {0.f, 0.f, 0.f, 0.f};
        ((f32x4*)dst_base)[8192 + u] = z4;         // null row of the copy
    }

    // ---- su-pair merge (lane <-> lane^32), then per-wave partials to LDS ----
    {
        float Mo = __shfl_xor(M1, 32), Zo = __shfl_xor(Z1, 32);
        float Sabo = __shfl_xor(Sab, 32), Scwo = __shfl_xor(Scw, 32);
        float ax = __shfl_xor(A.x, 32), ay = __shfl_xor(A.y, 32);
        float az = __shfl_xor(A.z, 32), aw = __shfl_xor(A.w, 32);
        float mn = fmaxf(M1, Mo);
        float s0 = __expf(M1 - mn), s1 = __expf(Mo - mn);
        Z1  = Z1*s0  + Zo*s1;
        Sab = Sab*s0 + Sabo*s1;
        Scw = Scw*s0 + Scwo*s1;
        A.x = A.x*s0 + ax*s1;  A.y = A.y*s0 + ay*s1;
        A.z = A.z*s0 + az*s1;  A.w = A.w*s0 + aw*s1;
        M1 = mn;

        float Mo2 = __shfl_xor(M2, 32), Zo2 = __shfl_xor(Z2, 32);
        float S1o = __shfl_xor(S1, 32), S2o = __shfl_xor(S2, 32);
        float mn2 = fmaxf(M2, Mo2);
        float t0 = __expf(M2 - mn2), t1 = __expf(Mo2 - mn2);
        Z2 = Z2*t0 + Zo2*t1;
        S1 = S1*t0 + S1o*t1;
        S2 = S2*t0 + S2o*t1;
        M2 = mn2;

        if (lane < 32) {
            lds_accs[wave][c] = make_float4(A.x, A.y, A.z, A.w);
            if (c == 0) lds_w1[wave] = make_float4(M1, Z1, Sab, 0.f);
            if (mq == 0) {
                lds_scw[wave][n] = Scw;
                lds_loo[wave][n] = make_float4(M2, Z2, S1, S2);
            }
        }
    }
    BAR();   // b1: tot + all per-wave partials ready

    // ---- stage A: final merges ----
    if (u < 32) {
        // item_allocation (+ u==0: ab, mzf)
        float4 w1 = lds_w1[0];
        float Mm = w1.x, Zm = w1.y, Sabm = w1.z;
        float4 Am = lds_accs[0][u];
#pragma unroll
        for (int j = 1; j < 4; ++j) {
            float4 wj = lds_w1[j];
            float4 Aj = lds_accs[j][u];
            float mn = fmaxf(Mm, wj.x);
            float s0 = __expf(Mm - mn), s1 = __expf(wj.x - mn);
            Zm   = Zm*s0   + wj.y*s1;
            Sabm = Sabm*s0 + wj.z*s1;
            Am.x = Am.x*s0 + Aj.x*s1;  Am.y = Am.y*s0 + Aj.y*s1;
            Am.z = Am.z*s0 + Aj.z*s1;  Am.w = Am.w*s0 + Aj.w*s1;
            Mm = mn;
        }
        float M1f = fmaxf(Mm, 0.f);                // null entry x=0
        float s0 = __expf(Mm - M1f);
        float Z1f = Zm*s0 + __expf(-M1f);
        float inv = 1.f / Z1f;
        float sf = s0 * inv;
        ((float4*)(out_item + bb_ * NM))[u] =
            make_float4(Am.x*sf, Am.y*sf, Am.z*sf, Am.w*sf);
        if (u == 0) {
            lds_ab = Sabm * sf;
            lds_mzf = make_float2(M1f, inv);
        }
    } else if (u < 40) {
        // LOO finalize for agent i
        const int i = u - 32;
        float4 L = lds_loo[0][i];
        float Mm = L.x, Zm = L.y, S1m = L.z, S2m = L.w;
#pragma unroll
        for (int j = 1; j < 4; ++j) {
            float4 Lj = lds_loo[j][i];
            float mn = fmaxf(Mm, Lj.x);
            float s0 = __expf(Mm - mn), s1 = __expf(Lj.x - mn);
            Zm  = Zm*s0  + Lj.y*s1;
            S1m = S1m*s0 + Lj.z*s1;
            S2m = S2m*s0 + Lj.w*s1;
            Mm = mn;
        }
        float M2f = fmaxf(Mm, 0.f);                // null: tr=0, b=0
        float s0 = __expf(Mm - M2f);
        float Z2f = Zm*s0 + __expf(-M2f);
        lds_rcs[i] = S1m*s0 / Z2f;
        lds_rb[i]  = S2m*s0 / Z2f;
    } else if (u < 48) {
        // chosen-welfare finalize for agent i
        const int i = u - 40;
        float4 w1 = lds_w1[0];
        float Mm = w1.x, Zm = w1.y;
        float Sm = lds_scw[0][i];
#pragma unroll
        for (int j = 1; j < 4; ++j) {
            float4 wj = lds_w1[j];
            float mn = fmaxf(Mm, wj.x);
            float s0 = __expf(Mm - mn), s1 = __expf(wj.x - mn);
            Zm = Zm*s0 + wj.y*s1;
            Sm = Sm*s0 + lds_scw[j][i]*s1;
            Mm = mn;
        }
        float M1f = fmaxf(Mm, 0.f);
        float s0 = __expf(Mm - M1f);
        float Z1f = Zm*s0 + __expf(-M1f);
        lds_cw[i] = Sm*s0 / Z1f;
    }
    BAR();   // b2: ab/mzf/rcs/rb/cw ready

    // ---- stage B: out_choice (all threads) + payments (8 threads) ----
    {
        float2 mzf = lds_mzf;
        float x = (lds_tot[u] + lds_bb[u]) * temp;
        out_choice[bb_ * SFULL + u] = __expf(x - mzf.x) * mzf.y;
        if (u == 0)
            out_choice[bb_ * SFULL + MENU] = __expf(-mzf.x) * mzf.y;
    }
    if (u < NAGENTS) {
        float ctot = 0.f;
#pragma unroll
        for (int k = 0; k < NAGENTS; ++k) ctot += lds_cw[k];
        float pay = (lds_rcs[u] + lds_rb[u] - (ctot - lds_cw[u]) - lds_ab)
                    / wvec[bb_ * NAGENTS + u];
        out_pay[(size_t)u * Bsz + bb_] = pay;
    }
}

extern "C" void kernel_launch(void* const* d_in, const int* in_sizes, int n_in,
                              void* d_out, int out_size, void* d_ws, size_t ws_size,
                              hipStream_t stream) {
    const float* bids   = (const float*)d_in[0];
    const float* allocs = (const float*)d_in[1];
    const float* wvec   = (const float*)d_in[2];
    const float* bvec   = (const float*)d_in[3];
    const float* tempp  = (const float*)d_in[4];
    float* out = (float*)d_out;
    const int Bsz = in_sizes[0] / NM;          // 4096
    cama_kernel<<<Bsz, 256, 0, stream>>>(bids, allocs, wvec, bvec, tempp,
                                         out, Bsz);
}

// Round 20
// 221.389 us; speedup vs baseline: 2.3523x; 1.0310x over previous
//
#include <hip/hip_runtime.h>

#define NAGENTS 8
#define NM 128          // NAGENTS*MITEMS
#define MENU 256
#define SFULL 257       // MENU + null entry

typedef float f32x4 __attribute__((ext_vector_type(4)));

// Raw barrier: wait LDS ops only (no vmcnt drain — copy-out stores and any
// in-flight loads keep flying across phases).
#define BAR() asm volatile("s_waitcnt lgkmcnt(0)\n\ts_barrier" ::: "memory")

// 256 threads/block, one auction per block, (256,5) => ~102 VGPR cap,
// 20 waves/CU. Streaming pass via ONE inline-asm block per 8-chunk group:
//   8x global_load_dwordx4 -> s_waitcnt vmcnt(0) -> 8x global_store_dwordx4
// = 8KB read run / 8KB write run, 4 turnaround pairs per pass (R19's 4-deep
// runs at 8 pairs measured 228.2us, best; run-length scaling says deeper is
// better). Registers are asm-pinned so hipcc cannot re-schedule or spill the
// batch (R8/R13/R18 failure mode). Store vmcnt clears on VGPR data-read, so
// the in-group vmcnt(0) mostly prices load latency, hidden by 20 waves/CU.
// Fully-online softmax families (R15); merge tail unchanged.
__global__ __launch_bounds__(256, 5) void cama_kernel(
    const float* __restrict__ bids,   // B,8,16
    const float* __restrict__ allocs, // B,256,8,16
    const float* __restrict__ wvec,   // B,8
    const float* __restrict__ bvec,   // B,256
    const float* __restrict__ tempp,  // 1
    float* __restrict__ out, int Bsz)
{
    __shared__ float lds_tot[MENU];                  // 1KB
    __shared__ float lds_bb[MENU];                   // 1KB
    __shared__ __align__(16) float4 lds_accs[4][32]; // 2KB item partials
    __shared__ __align__(16) float4 lds_w1[4];       // per-wave (M1,Z1,Sab,-)
    __shared__ __align__(16) float4 lds_loo[4][8];   // per-wave (M2,Z2,S1,S2)
    __shared__ float lds_scw[4][8];                  // per-wave Scw[n]
    __shared__ float lds_rcs[NAGENTS], lds_rb[NAGENTS], lds_cw[NAGENTS];
    __shared__ float lds_ab;
    __shared__ float2 lds_mzf;                       // (M1f, 1/Z1f)

    const int u = threadIdx.x;    // 0..255
    const int lane = u & 63;
    const int wave = u >> 6;      // 0..3
    const int c = u & 31;         // n = c>>2, item-quad mq = u&3
    const int n = c >> 2;
    const int mq = u & 3;
    const int su = u >> 5;        // s = 8k + su
    const size_t bb_ = (size_t)blockIdx.x;

    float* out_choice = out;                                  // B*257
    float* out_item   = out + (size_t)Bsz * SFULL;            // B*128
    float* out_pay    = out_item + (size_t)Bsz * NM;          // 8*B
    float* out_all    = out_pay + (size_t)NAGENTS * Bsz;      // B*257*128
    const float* src_base = allocs + bb_ * (MENU * NM);       // this block's payload
    float* dst_base = out_all + bb_ * (SFULL * NM);           // copy-out target

    const float temp = tempp[0];
    lds_bb[u] = bvec[bb_ * MENU + u];                    // 256 = blockDim
    const float4 q4 = ((const float4*)(bids + bb_ * NM))[c];   // L1 broadcast
    const float w_n = wvec[bb_ * NAGENTS + n];
    BAR();   // bb staged

    // online states
    float M1 = -1e30f, Z1 = 0.f, Sab = 0.f, Scw = 0.f;
    float4 A = make_float4(0.f, 0.f, 0.f, 0.f);
    float M2 = -1e30f, Z2 = 0.f, S1 = 0.f, S2 = 0.f;

    const int u16 = u << 4;   // byte offset of this thread's float4 in a chunk

    // ---- pass 1: streaming via pinned 8-load-run / 8-store-run asm groups ----
    for (int g = 0; g < 4; ++g) {
        const int o0 = (g << 15) + u16;          // chunk 8g+0, bytes
        const int o1 = o0 + 4096;
        const int o2 = o0 + 8192;
        const int o3 = o0 + 12288;
        const int o4 = o0 + 16384;
        const int o5 = o0 + 20480;
        const int o6 = o0 + 24576;
        const int o7 = o0 + 28672;
        f32x4 b0, b1, b2, b3, b4, b5, b6, b7;
        asm volatile(
            "global_load_dwordx4 %0, %8, %16 offset:0\n\t"
            "global_load_dwordx4 %1, %9, %16 offset:0\n\t"
            "global_load_dwordx4 %2, %10, %16 offset:0\n\t"
            "global_load_dwordx4 %3, %11, %16 offset:0\n\t"
            "global_load_dwordx4 %4, %12, %16 offset:0\n\t"
            "global_load_dwordx4 %5, %13, %16 offset:0\n\t"
            "global_load_dwordx4 %6, %14, %16 offset:0\n\t"
            "global_load_dwordx4 %7, %15, %16 offset:0\n\t"
            "s_waitcnt vmcnt(0)\n\t"
            "global_store_dwordx4 %8, %0, %17 offset:0\n\t"
            "global_store_dwordx4 %9, %1, %17 offset:0\n\t"
            "global_store_dwordx4 %10, %2, %17 offset:0\n\t"
            "global_store_dwordx4 %11, %3, %17 offset:0\n\t"
            "global_store_dwordx4 %12, %4, %17 offset:0\n\t"
            "global_store_dwordx4 %13, %5, %17 offset:0\n\t"
            "global_store_dwordx4 %14, %6, %17 offset:0\n\t"
            "global_store_dwordx4 %15, %7, %17 offset:0"
            : "=&v"(b0), "=&v"(b1), "=&v"(b2), "=&v"(b3),
              "=&v"(b4), "=&v"(b5), "=&v"(b6), "=&v"(b7)
            : "v"(o0), "v"(o1), "v"(o2), "v"(o3),
              "v"(o4), "v"(o5), "v"(o6), "v"(o7),
              "s"(src_base), "s"(dst_base)
            : "memory");

#pragma unroll
        for (int j = 0; j < 8; ++j) {
            f32x4 a4 = (j == 0) ? b0 : (j == 1) ? b1 : (j == 2) ? b2 :
                       (j == 3) ? b3 : (j == 4) ? b4 : (j == 5) ? b5 :
                       (j == 6) ? b6 : b7;
            const int s = (((g << 3) + j) << 3) + su;
            const float bbs = lds_bb[s];
            float util = a4[0]*q4.x + a4[1]*q4.y + a4[2]*q4.z + a4[3]*q4.w;
            util += __shfl_xor(util, 1);
            util += __shfl_xor(util, 2);           // item-dot for (s,n)
            float pwv = w_n * util;
            float t = pwv;
            t += __shfl_xor(t, 4);
            t += __shfl_xor(t, 8);
            t += __shfl_xor(t, 16);                // tot[s], all lanes
            if (c == 0) lds_tot[s] = t;
            // full-softmax family
            float x = (t + bbs) * temp;
            float mn = fmaxf(M1, x);
            float sc = __expf(M1 - mn);
            float p  = __expf(x - mn);
            Z1  = Z1*sc + p;
            A.x = A.x*sc + p*a4[0];
            A.y = A.y*sc + p*a4[1];
            A.z = A.z*sc + p*a4[2];
            A.w = A.w*sc + p*a4[3];
            Sab = Sab*sc + p*bbs;
            Scw = Scw*sc + p*pwv;
            M1 = mn;
            // leave-one-out family (own agent n)
            float tr = t - pwv;
            float x2 = (tr + bbs) * temp;
            float mn2 = fmaxf(M2, x2);
            float sc2 = __expf(M2 - mn2);
            float p2  = __expf(x2 - mn2);
            Z2 = Z2*sc2 + p2;
            S1 = S1*sc2 + p2*tr;
            S2 = S2*sc2 + p2*bbs;
            M2 = mn2;
        }
    }
    if (u < 32) {
        f32x4 z4 = {0.f, 0.f, 0.f, 0.f};
        ((f32x4*)dst_base)[8192 + u] = z4;         // null row of the copy
    }

    // ---- su-pair merge (lane <-> lane^32), then per-wave partials to LDS ----
    {
        float Mo = __shfl_xor(M1, 32), Zo = __shfl_xor(Z1, 32);
        float Sabo = __shfl_xor(Sab, 32), Scwo = __shfl_xor(Scw, 32);
        float ax = __shfl_xor(A.x, 32), ay = __shfl_xor(A.y, 32);
        float az = __shfl_xor(A.z, 32), aw = __shfl_xor(A.w, 32);
        float mn = fmaxf(M1, Mo);
        float s0 = __expf(M1 - mn), s1 = __expf(Mo - mn);
        Z1  = Z1*s0  + Zo*s1;
        Sab = Sab*s0 + Sabo*s1;
        Scw = Scw*s0 + Scwo*s1;
        A.x = A.x*s0 + ax*s1;  A.y = A.y*s0 + ay*s1;
        A.z = A.z*s0 + az*s1;  A.w = A.w*s0 + aw*s1;
        M1 = mn;

        float Mo2 = __shfl_xor(M2, 32), Zo2 = __shfl_xor(Z2, 32);
        float S1o = __shfl_xor(S1, 32), S2o = __shfl_xor(S2, 32);
        float mn2 = fmaxf(M2, Mo2);
        float t0 = __expf(M2 - mn2), t1 = __expf(Mo2 - mn2);
        Z2 = Z2*t0 + Zo2*t1;
        S1 = S1*t0 + S1o*t1;
        S2 = S2*t0 + S2o*t1;
        M2 = mn2;

        if (lane < 32) {
            lds_accs[wave][c] = make_float4(A.x, A.y, A.z, A.w);
            if (c == 0) lds_w1[wave] = make_float4(M1, Z1, Sab, 0.f);
            if (mq == 0) {
                lds_scw[wave][n] = Scw;
                lds_loo[wave][n] = make_float4(M2, Z2, S1, S2);
            }
        }
    }
    BAR();   // b1: tot + all per-wave partials ready

    // ---- stage A: final merges ----
    if (u < 32) {
        // item_allocation (+ u==0: ab, mzf)
        float4 w1 = lds_w1[0];
        float Mm = w1.x, Zm = w1.y, Sabm = w1.z;
        float4 Am = lds_accs[0][u];
#pragma unroll
        for (int j = 1; j < 4; ++j) {
            float4 wj = lds_w1[j];
            float4 Aj = lds_accs[j][u];
            float mn = fmaxf(Mm, wj.x);
            float s0 = __expf(Mm - mn), s1 = __expf(wj.x - mn);
            Zm   = Zm*s0   + wj.y*s1;
            Sabm = Sabm*s0 + wj.z*s1;
            Am.x = Am.x*s0 + Aj.x*s1;  Am.y = Am.y*s0 + Aj.y*s1;
            Am.z = Am.z*s0 + Aj.z*s1;  Am.w = Am.w*s0 + Aj.w*s1;
            Mm = mn;
        }
        float M1f = fmaxf(Mm, 0.f);                // null entry x=0
        float s0 = __expf(Mm - M1f);
        float Z1f = Zm*s0 + __expf(-M1f);
        float inv = 1.f / Z1f;
        float sf = s0 * inv;
        ((float4*)(out_item + bb_ * NM))[u] =
            make_float4(Am.x*sf, Am.y*sf, Am.z*sf, Am.w*sf);
        if (u == 0) {
            lds_ab = Sabm * sf;
            lds_mzf = make_float2(M1f, inv);
        }
    } else if (u < 40) {
        // LOO finalize for agent i
        const int i = u - 32;
        float4 L = lds_loo[0][i];
        float Mm = L.x, Zm = L.y, S1m = L.z, S2m = L.w;
#pragma unroll
        for (int j = 1; j < 4; ++j) {
            float4 Lj = lds_loo[j][i];
            float mn = fmaxf(Mm, Lj.x);
            float s0 = __expf(Mm - mn), s1 = __expf(Lj.x - mn);
            Zm  = Zm*s0  + Lj.y*s1;
            S1m = S1m*s0 + Lj.z*s1;
            S2m = S2m*s0 + Lj.w*s1;
            Mm = mn;
        }
        float M2f = fmaxf(Mm, 0.f);                // null: tr=0, b=0
        float s0 = __expf(Mm - M2f);
        float Z2f = Zm*s0 + __expf(-M2f);
        lds_rcs[i] = S1m*s0 / Z2f;
        lds_rb[i]  = S2m*s0 / Z2f;
    } else if (u < 48) {
        // chosen-welfare finalize for agent i
        const int i = u - 40;
        float4 w1 = lds_w1[0];
        float Mm = w1.x, Zm = w1.y;
        float Sm = lds_scw[0][i];
#pragma unroll
        for (int j = 1; j < 4; ++j) {
            float4 wj = lds_w1[j];
            float mn = fmaxf(Mm, wj.x);
            float s0 = __expf(Mm - mn), s1 = __expf(wj.x - mn);
            Zm = Zm*s0 + wj.y*s1;
            Sm = Sm*s0 + lds_scw[j][i]*s1;
            Mm = mn;
        }
        float M1f = fmaxf(Mm, 0.f);
        float s0 = __expf(Mm - M1f);
        float Z1f = Zm*s0 + __expf(-M1f);
        lds_cw[i] = Sm*s0 / Z1f;
    }
    BAR();   // b2: ab/mzf/rcs/rb/cw ready

    // ---- stage B: out_choice (all threads) + payments (8 threads) ----
    {
        float2 mzf = lds_mzf;
        float x = (lds_tot[u] + lds_bb[u]) * temp;
        out_choice[bb_ * SFULL + u] = __expf(x - mzf.x) * mzf.y;
        if (u == 0)
            out_choice[bb_ * SFULL + MENU] = __expf(-mzf.x) * mzf.y;
    }
    if (u < NAGENTS) {
        float ctot = 0.f;
#pragma unroll
        for (int k = 0; k < NAGENTS; ++k) ctot += lds_cw[k];
        float pay = (lds_rcs[u] + lds_rb[u] - (ctot - lds_cw[u]) - lds_ab)
                    / wvec[bb_ * NAGENTS + u];
        out_pay[(size_t)u * Bsz + bb_] = pay;
    }
}

extern "C" void kernel_launch(void* const* d_in, const int* in_sizes, int n_in,
                              void* d_out, int out_size, void* d_ws, size_t ws_size,
                              hipStream_t stream) {
    const float* bids   = (const float*)d_in[0];
    const float* allocs = (const float*)d_in[1];
    const float* wvec   = (const float*)d_in[2];
    const float* bvec   = (const float*)d_in[3];
    const float* tempp  = (const float*)d_in[4];
    float* out = (float*)d_out;
    const int Bsz = in_sizes[0] / NM;          // 4096
    cama_kernel<<<Bsz, 256, 0, stream>>>(bids, allocs, wvec, bvec, tempp,
                                         out, Bsz);
}